// Round 2
// 217.872 us; speedup vs baseline: 1.0077x; 1.0077x over previous
//
#include <hip/hip_runtime.h>
#include <hip/hip_bf16.h>
#include <math.h>

typedef __attribute__((ext_vector_type(8))) short short8;
typedef __attribute__((ext_vector_type(8))) unsigned short us8;
typedef __attribute__((ext_vector_type(4))) float f32x4;

__device__ inline unsigned short f2bf(float f) {
    unsigned int u = __float_as_uint(f);
    unsigned int r = u + 0x7fffu + ((u >> 16) & 1u);   // RTNE
    return (unsigned short)(r >> 16);
}
__device__ inline float bf2f(unsigned short h) {
    return __uint_as_float(((unsigned int)h) << 16);
}

// async global->LDS, 16 B per lane; LDS dest = wave-uniform base + lane*16
__device__ __forceinline__ void gld16(const unsigned short* g, unsigned short* l) {
    __builtin_amdgcn_global_load_lds(
        (const __attribute__((address_space(1))) unsigned int*)g,
        (__attribute__((address_space(3))) unsigned int*)l, 16, 0, 0);
}

// ---------------- fused prep: convX (float4-vectorized) + LDS-tiled W1/W2 transpose + degree count ----

__global__ __launch_bounds__(256) void prep_kernel(
    const float* __restrict__ x, unsigned short* __restrict__ Xh,
    const float* __restrict__ W1, unsigned short* __restrict__ W1hT,
    const float* __restrict__ W2, unsigned short* __restrict__ W2hT,
    const int* __restrict__ dst, int* __restrict__ deg,
    int M, int K1, int Kp1, int H, int E,
    int bX, int bT1, int bT2)
{
    __shared__ unsigned short T[64][65];
    const int b = blockIdx.x;
    const int tid = threadIdx.x;
    if (b < bX) {
        // X convert, 4 elems/thread (K1 % 4 == 0; k >= K1 zero-pad)
        int id = b * 256 + tid;                 // float4 index
        int kp4 = Kp1 >> 2;                     // 200
        int k14 = K1 >> 2;                      // 196
        if (id < M * kp4) {
            int r = id / kp4;
            int k4 = id - r * kp4;
            ushort4 o;
            if (k4 < k14) {
                float4 v = *(const float4*)&x[(size_t)r * K1 + k4 * 4];
                o.x = f2bf(v.x); o.y = f2bf(v.y); o.z = f2bf(v.z); o.w = f2bf(v.w);
            } else {
                o.x = o.y = o.z = o.w = 0;
            }
            *(ushort4*)&Xh[(size_t)r * Kp1 + k4 * 4] = o;
        }
    } else if (b < bX + bT1) {
        // W1 [784,512] -> W1hT [512,800]
        int t = b - bX;
        int kt = t >> 3;              // 13 k-tiles
        int nt = t & 7;               // 8 n-tiles
        int k0 = kt * 64, n0 = nt * 64;
        int nl = tid & 63, kl0 = tid >> 6;
#pragma unroll
        for (int j = 0; j < 16; j++) {
            int k = k0 + kl0 + j * 4;
            float v = (k < K1) ? W1[(size_t)k * H + n0 + nl] : 0.f;
            T[kl0 + j * 4][nl] = f2bf(v);
        }
        __syncthreads();
        int kl = tid & 63, nl0 = tid >> 6;
#pragma unroll
        for (int j = 0; j < 16; j++) {
            int k = k0 + kl;
            if (k < Kp1) W1hT[(size_t)(n0 + nl0 + j * 4) * Kp1 + k] = T[kl][nl0 + j * 4];
        }
    } else if (b < bX + bT1 + bT2) {
        // W2 [512,512] -> W2hT [512,512]
        int t = b - bX - bT1;
        int kt = t >> 3, nt = t & 7;
        int k0 = kt * 64, n0 = nt * 64;
        int nl = tid & 63, kl0 = tid >> 6;
#pragma unroll
        for (int j = 0; j < 16; j++) {
            int k = k0 + kl0 + j * 4;
            T[kl0 + j * 4][nl] = f2bf(W2[(size_t)k * H + n0 + nl]);
        }
        __syncthreads();
        int kl = tid & 63, nl0 = tid >> 6;
#pragma unroll
        for (int j = 0; j < 16; j++)
            W2hT[(size_t)(n0 + nl0 + j * 4) * H + k0 + kl] = T[kl][nl0 + j * 4];
    } else {
        int e = (b - bX - bT1 - bT2) * 256 + tid;
        if (e < E) atomicAdd(&deg[dst[e]], 1);
    }
}

// ---------------- one-block scan (1024 threads, prefetched) -> row_start + cursor; also dinv ----------------

__global__ __launch_bounds__(1024) void scan_kernel(const int* __restrict__ deg,
                                                    int* __restrict__ row_start,
                                                    int* __restrict__ cursor,
                                                    float* __restrict__ dinv, int n)
{
    __shared__ int swave[16];
    __shared__ int s_run;
    const int lane = threadIdx.x & 63;
    const int w = threadIdx.x >> 6;
    if (threadIdx.x == 0) s_run = 0;
    __syncthreads();

    const int nch = (n + 1023) >> 10;      // 10 for n=10000 (max 16 supported)
    int vv[16];
#pragma unroll 4
    for (int j = 0; j < nch; j++) {
        int i = j * 1024 + threadIdx.x;
        vv[j] = (i < n) ? deg[i] : 0;      // all loads issued up front, latency overlapped
    }

    for (int j = 0; j < nch; j++) {
        int i = j * 1024 + threadIdx.x;
        int v = vv[j];
        int incl = v;
#pragma unroll
        for (int off = 1; off < 64; off <<= 1) {
            int t = __shfl_up(incl, off);
            if (lane >= off) incl += t;
        }
        if (lane == 63) swave[w] = incl;
        __syncthreads();
        int wpre = 0, total = 0;
#pragma unroll
        for (int jj = 0; jj < 16; jj++) {
            int sv = swave[jj];
            if (jj < w) wpre += sv;
            total += sv;
        }
        int run = s_run;
        if (i < n) {
            int rs = run + wpre + incl - v;
            row_start[i] = rs;
            cursor[i] = rs;
            dinv[i] = rsqrtf((float)v + 1.0f);
        }
        __syncthreads();
        if (threadIdx.x == 0) s_run = run + total;
        __syncthreads();
    }
    if (threadIdx.x == 0) row_start[n] = s_run;
}

// ---------------- MFMA GEMM 128x128 (m97 structure) (+ optional fused CSR-fill blocks) ----------------

#define TBK 32

__global__ __launch_bounds__(256) void gemm_mfma_kernel(
    const unsigned short* __restrict__ AhG,
    const unsigned short* __restrict__ WhT,
    unsigned short* __restrict__ Hb, int M, int N, int Kp, int tiles_m,
    int gemmBlocks,
    const int* __restrict__ src, const int* __restrict__ dst,
    int* __restrict__ cursor, int* __restrict__ csr_src, int E)
{
    const int blk = blockIdx.x;
    if (blk >= gemmBlocks) {
        int e = (blk - gemmBlocks) * 256 + threadIdx.x;
        if (e < E) {
            int d = dst[e];
            int pos = atomicAdd(&cursor[d], 1);
            csr_src[pos] = src[e];
        }
        return;
    }

    const int tn = blk & 3;          // N = 512 -> 4 col tiles of 128
    const int tm = blk >> 2;

    __shared__ unsigned short Ah[128 * TBK];   // 8 KB
    __shared__ unsigned short Bh[128 * TBK];   // 8 KB

    const int tid  = threadIdx.x;
    const int wave = tid >> 6;
    const int lane = tid & 63;
    const int quad = lane >> 4;
    const int l16  = lane & 15;
    const int row0 = tm * 128;
    const int col0 = tn * 128;
    const int wr = (wave >> 1) * 64;   // wave quadrant rows
    const int wc = (wave & 1) * 64;    // wave quadrant cols

    // staging: each wave stages 32 rows of A and 32 rows of B^T (2x gld16 each)
    const int srow = lane >> 2;
    const int skc  = (lane & 3) * 8;
    int ga0 = row0 + wave * 32 + srow;        if (ga0 >= M) ga0 = M - 1;
    int ga1 = row0 + wave * 32 + 16 + srow;   if (ga1 >= M) ga1 = M - 1;
    const unsigned short* gA0 = AhG + (size_t)ga0 * Kp + skc;
    const unsigned short* gA1 = AhG + (size_t)ga1 * Kp + skc;
    const unsigned short* gB0 = WhT + (size_t)(col0 + wave * 32 + srow) * Kp + skc;
    const unsigned short* gB1 = WhT + (size_t)(col0 + wave * 32 + 16 + srow) * Kp + skc;
    unsigned short* lA0 = &Ah[(wave * 32) * TBK];
    unsigned short* lA1 = &Ah[(wave * 32 + 16) * TBK];
    unsigned short* lB0 = &Bh[(wave * 32) * TBK];
    unsigned short* lB1 = &Bh[(wave * 32 + 16) * TBK];

    f32x4 acc[4][4];
#pragma unroll
    for (int b = 0; b < 4; b++)
#pragma unroll
        for (int c = 0; c < 4; c++) acc[b][c] = (f32x4){0.f, 0.f, 0.f, 0.f};

    for (int k0 = 0; k0 < Kp; k0 += TBK) {
        gld16(gA0 + k0, lA0);
        gld16(gA1 + k0, lA1);
        gld16(gB0 + k0, lB0);
        gld16(gB1 + k0, lB1);
        __syncthreads();

        short8 ah[4], bh[4];
#pragma unroll
        for (int b = 0; b < 4; b++)
            ah[b] = *(const short8*)&Ah[(wr + b * 16 + l16) * TBK + quad * 8];
#pragma unroll
        for (int c = 0; c < 4; c++)
            bh[c] = *(const short8*)&Bh[(wc + c * 16 + l16) * TBK + quad * 8];
#pragma unroll
        for (int c = 0; c < 4; c++)
#pragma unroll
            for (int b = 0; b < 4; b++)
                acc[b][c] = __builtin_amdgcn_mfma_f32_16x16x32_bf16(ah[b], bh[c], acc[b][c], 0, 0, 0);
        __syncthreads();
    }

#pragma unroll
    for (int b = 0; b < 4; b++) {
#pragma unroll
        for (int c = 0; c < 4; c++) {
            int gc = col0 + wc + c * 16 + l16;
#pragma unroll
            for (int r = 0; r < 4; r++) {
                int gr = row0 + wr + b * 16 + quad * 4 + r;
                if (gr < M) Hb[(size_t)gr * N + gc] = f2bf(acc[b][c][r]);
            }
        }
    }
}

// ---------------- gather aggregation, F=512: wave per node, unroll-8, no LDS/barriers ----------------

__global__ __launch_bounds__(256) void gather512_kernel(
    const unsigned short* __restrict__ hb,
    unsigned short* __restrict__ out_h,
    const int* __restrict__ csr_src, const int* __restrict__ row_start,
    const float* __restrict__ dinv, const float* __restrict__ bias, int n)
{
    const int wv = threadIdx.x >> 6;
    const int lane = threadIdx.x & 63;
    const int node = blockIdx.x * 4 + wv;
    if (node >= n) return;
    const float di = dinv[node];
    const int fo = lane * 8;

    us8 self = *(const us8*)&hb[(size_t)node * 512 + fo];
    float4 b0 = *(const float4*)&bias[fo];
    float4 b1 = *(const float4*)&bias[fo + 4];
    const float dd = di * di;
    float acc[8];
    acc[0] = dd * bf2f(self[0]) + b0.x;
    acc[1] = dd * bf2f(self[1]) + b0.y;
    acc[2] = dd * bf2f(self[2]) + b0.z;
    acc[3] = dd * bf2f(self[3]) + b0.w;
    acc[4] = dd * bf2f(self[4]) + b1.x;
    acc[5] = dd * bf2f(self[5]) + b1.y;
    acc[6] = dd * bf2f(self[6]) + b1.z;
    acc[7] = dd * bf2f(self[7]) + b1.w;

    int p = row_start[node];
    const int end = row_start[node + 1];
    for (; p + 7 < end; p += 8) {
        int s[8];
#pragma unroll
        for (int u = 0; u < 8; u++) s[u] = csr_src[p + u];
        us8 r[8];
#pragma unroll
        for (int u = 0; u < 8; u++) r[u] = *(const us8*)&hb[(size_t)s[u] * 512 + fo];
        float w[8];
#pragma unroll
        for (int u = 0; u < 8; u++) w[u] = dinv[s[u]] * di;
#pragma unroll
        for (int i = 0; i < 8; i++) {
            float t = acc[i];
#pragma unroll
            for (int u = 0; u < 8; u++) t += w[u] * bf2f(r[u][i]);
            acc[i] = t;
        }
    }
    for (; p + 3 < end; p += 4) {
        int s0 = csr_src[p], s1 = csr_src[p + 1], s2 = csr_src[p + 2], s3 = csr_src[p + 3];
        float w0 = dinv[s0] * di, w1 = dinv[s1] * di, w2 = dinv[s2] * di, w3 = dinv[s3] * di;
        us8 r0 = *(const us8*)&hb[(size_t)s0 * 512 + fo];
        us8 r1 = *(const us8*)&hb[(size_t)s1 * 512 + fo];
        us8 r2 = *(const us8*)&hb[(size_t)s2 * 512 + fo];
        us8 r3 = *(const us8*)&hb[(size_t)s3 * 512 + fo];
#pragma unroll
        for (int i = 0; i < 8; i++)
            acc[i] += w0 * bf2f(r0[i]) + w1 * bf2f(r1[i]) + w2 * bf2f(r2[i]) + w3 * bf2f(r3[i]);
    }
    for (; p < end; ++p) {
        int s = csr_src[p];
        float w = dinv[s] * di;
        us8 r = *(const us8*)&hb[(size_t)s * 512 + fo];
#pragma unroll
        for (int i = 0; i < 8; i++) acc[i] += w * bf2f(r[i]);
    }

    us8 o;
#pragma unroll
    for (int i = 0; i < 8; i++) o[i] = f2bf(fmaxf(acc[i], 0.f));
    *(us8*)&out_h[(size_t)node * 512 + fo] = o;
}

// ---------------- small GEMM via MFMA, hi/lo-split Wc (f32-accurate): h3[M,10] = A[M,512] @ Wc ----------------

__global__ __launch_bounds__(256) void gemm_small_kernel(
    const unsigned short* __restrict__ Ahp,
    const float* __restrict__ W, float* __restrict__ C, int M, int K)
{
    // WT[part][col][k], col stride 520 shorts (1040 B) to break the 1024 B bank period
    __shared__ unsigned short WT[2][16 * 520];
    const int tid = threadIdx.x;
#pragma unroll
    for (int c = 0; c < 10; c++) {
        for (int k = tid; k < 512; k += 256) {
            float v = W[(size_t)k * 10 + c];
            unsigned short hi = f2bf(v);
            float lo = v - bf2f(hi);
            WT[0][c * 520 + k] = hi;
            WT[1][c * 520 + k] = f2bf(lo);
        }
    }
#pragma unroll
    for (int c = 10; c < 16; c++) {
        for (int k = tid; k < 512; k += 256) {
            WT[0][c * 520 + k] = 0;
            WT[1][c * 520 + k] = 0;
        }
    }
    __syncthreads();

    const int wave = tid >> 6;
    const int lane = tid & 63;
    const int quad = lane >> 4;
    const int l16  = lane & 15;
    int row = blockIdx.x * 64 + wave * 16 + l16;
    if (row >= M) row = M - 1;
    const unsigned short* ga = Ahp + (size_t)row * K + quad * 8;

    f32x4 acc = (f32x4){0.f, 0.f, 0.f, 0.f};
    for (int k0 = 0; k0 < 512; k0 += 32) {
        short8 a   = *(const short8*)(ga + k0);
        short8 bhi = *(const short8*)&WT[0][l16 * 520 + k0 + quad * 8];
        short8 blo = *(const short8*)&WT[1][l16 * 520 + k0 + quad * 8];
        acc = __builtin_amdgcn_mfma_f32_16x16x32_bf16(a, bhi, acc, 0, 0, 0);
        acc = __builtin_amdgcn_mfma_f32_16x16x32_bf16(a, blo, acc, 0, 0, 0);
    }

    if (l16 < 10) {
        int gr0 = blockIdx.x * 64 + wave * 16 + quad * 4;
#pragma unroll
        for (int r = 0; r < 4; r++) {
            int gr = gr0 + r;
            if (gr < M) C[(size_t)gr * 10 + l16] = acc[r];
        }
    }
}

// ---------------- fused gather(F=10) + log_softmax: WAVE per node ----------------
// Lanes = edge-group (0..5) x class (0..9); 6 edges x 10 classes per iteration.
// Cross-group reduce via shuffles; softmax on lanes 0..9; coalesced 40 B stores.

__global__ __launch_bounds__(256) void gather10_softmax_kernel(
    const float* __restrict__ h3, float* __restrict__ out,
    const int* __restrict__ csr_src, const int* __restrict__ row_start,
    const float* __restrict__ dinv, const float* __restrict__ bc, int n)
{
    const int wv = threadIdx.x >> 6;
    const int lane = threadIdx.x & 63;
    const int node = blockIdx.x * 4 + wv;
    if (node >= n) return;

    const int eg = lane / 10;          // 0..5 (lane<60), 6 for lanes 60..63
    const int c  = lane - eg * 10;
    const bool active = lane < 60;
    const float di = dinv[node];
    const int beg = row_start[node], end = row_start[node + 1];

    float acc = 0.f;
    if (active) {
        for (int p = beg + eg; p < end; p += 6) {
            int s = csr_src[p];
            acc += h3[(size_t)s * 10 + c] * dinv[s];
        }
        acc *= di;
    }
    // reduce eg-groups: lanes (c, c+10, ..., c+50) -> lane c
    acc += __shfl(acc, lane + 30);                         // lanes 0..29 pick up eg+3
    float t1 = __shfl(acc, lane + 10);
    float t2 = __shfl(acc, lane + 20);
    if (lane < 10) {
        acc = acc + t1 + t2 + h3[(size_t)node * 10 + c] * di * di + bc[c];
    }
    float vj[10];
#pragma unroll
    for (int j = 0; j < 10; j++) vj[j] = __shfl(acc, j);
    if (lane < 10) {
        float m = vj[0];
#pragma unroll
        for (int j = 1; j < 10; j++) m = fmaxf(m, vj[j]);
        float ssum = 0.f;
#pragma unroll
        for (int j = 0; j < 10; j++) ssum += __expf(vj[j] - m);
        out[(size_t)node * 10 + c] = acc - (m + __logf(ssum));
    }
}

// ---------------- launch ----------------

extern "C" void kernel_launch(void* const* d_in, const int* in_sizes, int n_in,
                              void* d_out, int out_size, void* d_ws, size_t ws_size,
                              hipStream_t stream)
{
    const float* x   = (const float*)d_in[0];
    const int*   ei  = (const int*)d_in[1];
    const float* W1  = (const float*)d_in[2];
    const float* b1  = (const float*)d_in[3];
    const float* W2  = (const float*)d_in[4];
    const float* b2  = (const float*)d_in[5];
    const float* Wc  = (const float*)d_in[6];
    const float* bc  = (const float*)d_in[7];
    float* out = (float*)d_out;

    const int IN_FEATS = 784;
    const int KP1 = 800;
    const int H = 512;
    const int NC = 10;
    const int n = in_sizes[0] / IN_FEATS;   // 10000
    const int E = in_sizes[1] / 2;          // 160000
    const int* src = ei;
    const int* dst = ei + E;

    // workspace layout (~40 MB)
    char* ws = (char*)d_ws;
    unsigned short* Hb   = (unsigned short*)ws; ws += (size_t)n * H * sizeof(unsigned short);
    unsigned short* Xh   = (unsigned short*)ws; ws += (size_t)n * KP1 * sizeof(unsigned short);
    unsigned short* AhB  = (unsigned short*)ws; ws += (size_t)n * H * sizeof(unsigned short);
    unsigned short* W1hT = (unsigned short*)ws; ws += (size_t)KP1 * H * sizeof(unsigned short);
    unsigned short* W2hT = (unsigned short*)ws; ws += (size_t)H * H * sizeof(unsigned short);
    float* dinv      = (float*)ws;             ws += (size_t)n * sizeof(float);
    int*   deg       = (int*)ws;               ws += (size_t)n * sizeof(int);
    int*   cursor    = (int*)ws;               ws += (size_t)n * sizeof(int);
    int*   csr_src   = (int*)ws;               ws += (size_t)E * sizeof(int);
    int*   row_start = (int*)ws;               ws += (size_t)(n + 1) * sizeof(int);
    float* h3        = (float*)ws;             ws += (size_t)n * NC * sizeof(float);

    hipMemsetAsync(deg, 0, (size_t)n * sizeof(int), stream);

    // ---- fused prep ----
    const int bX  = ((size_t)n * (KP1 / 4) + 255) / 256;   // 7813
    const int bT1 = ((KP1 + 63) / 64) * (H / 64);          // 104
    const int bT2 = (H / 64) * (H / 64);                   // 64
    const int bE  = (E + 255) / 256;                       // 625
    prep_kernel<<<bX + bT1 + bT2 + bE, 256, 0, stream>>>(
        x, Xh, W1, W1hT, W2, W2hT, dst, deg,
        n, IN_FEATS, KP1, H, E, bX, bT1, bT2);

    scan_kernel<<<1, 1024, 0, stream>>>(deg, row_start, cursor, dinv, n);

    const int tiles_m = (n + 127) / 128;                    // 79
    const int gemmBlocks = tiles_m * 4;                     // 316 (128x128 tiles, N=512)

    // ---- layer 1 (+ CSR fill riding the dispatch) ----
    gemm_mfma_kernel<<<gemmBlocks + bE, 256, 0, stream>>>(
        Xh, W1hT, Hb, n, H, KP1, tiles_m, gemmBlocks, src, dst, cursor, csr_src, E);
    gather512_kernel<<<(n + 3) / 4, 256, 0, stream>>>(Hb, AhB, csr_src, row_start, dinv, b1, n);

    // ---- layer 2 ----
    gemm_mfma_kernel<<<gemmBlocks, 256, 0, stream>>>(
        AhB, W2hT, Hb, n, H, H, tiles_m, gemmBlocks, src, dst, cursor, csr_src, 0);
    gather512_kernel<<<(n + 3) / 4, 256, 0, stream>>>(Hb, AhB, csr_src, row_start, dinv, b2, n);

    // ---- layer 3 + softmax ----
    gemm_small_kernel<<<(n + 63) / 64, 256, 0, stream>>>(AhB, Wc, h3, n, H);
    gather10_softmax_kernel<<<(n + 3) / 4, 256, 0, stream>>>(h3, out, csr_src, row_start, dinv, bc, n);
}

// Round 3
// 204.659 us; speedup vs baseline: 1.0728x; 1.0646x over previous
//
#include <hip/hip_runtime.h>
#include <hip/hip_bf16.h>
#include <math.h>

typedef __attribute__((ext_vector_type(8))) short short8;
typedef __attribute__((ext_vector_type(8))) unsigned short us8;
typedef __attribute__((ext_vector_type(4))) float f32x4;

__device__ inline unsigned short f2bf(float f) {
    unsigned int u = __float_as_uint(f);
    unsigned int r = u + 0x7fffu + ((u >> 16) & 1u);   // RTNE
    return (unsigned short)(r >> 16);
}
__device__ inline float bf2f(unsigned short h) {
    return __uint_as_float(((unsigned int)h) << 16);
}

// async global->LDS, 16 B per lane; LDS dest = wave-uniform base + lane*16
__device__ __forceinline__ void gld16(const unsigned short* g, unsigned short* l) {
    __builtin_amdgcn_global_load_lds(
        (const __attribute__((address_space(1))) unsigned int*)g,
        (__attribute__((address_space(3))) unsigned int*)l, 16, 0, 0);
}

// ---------------- fused prep: convX + W1/W2 transpose + degree count + bucket-CSR fill ----------------
// Bucket CSR: one atomicAdd both counts degree and assigns the slot. No scan pass needed.

__global__ __launch_bounds__(256) void prep_kernel(
    const float* __restrict__ x, unsigned short* __restrict__ Xh,
    const float* __restrict__ W1, unsigned short* __restrict__ W1hT,
    const float* __restrict__ W2, unsigned short* __restrict__ W2hT,
    const int* __restrict__ src, const int* __restrict__ dst,
    int* __restrict__ deg, int* __restrict__ csr_pad,
    int M, int K1, int Kp1, int H, int E,
    int bX, int bT1, int bT2)
{
    __shared__ unsigned short T[64][65];
    const int b = blockIdx.x;
    const int tid = threadIdx.x;
    if (b < bX) {
        // X convert, 4 elems/thread (K1 % 4 == 0; k >= K1 zero-pad)
        int id = b * 256 + tid;                 // float4 index
        int kp4 = Kp1 >> 2;                     // 200
        int k14 = K1 >> 2;                      // 196
        if (id < M * kp4) {
            int r = id / kp4;
            int k4 = id - r * kp4;
            ushort4 o;
            if (k4 < k14) {
                float4 v = *(const float4*)&x[(size_t)r * K1 + k4 * 4];
                o.x = f2bf(v.x); o.y = f2bf(v.y); o.z = f2bf(v.z); o.w = f2bf(v.w);
            } else {
                o.x = o.y = o.z = o.w = 0;
            }
            *(ushort4*)&Xh[(size_t)r * Kp1 + k4 * 4] = o;
        }
    } else if (b < bX + bT1) {
        // W1 [784,512] -> W1hT [512,800]
        int t = b - bX;
        int kt = t >> 3;              // 13 k-tiles
        int nt = t & 7;               // 8 n-tiles
        int k0 = kt * 64, n0 = nt * 64;
        int nl = tid & 63, kl0 = tid >> 6;
#pragma unroll
        for (int j = 0; j < 16; j++) {
            int k = k0 + kl0 + j * 4;
            float v = (k < K1) ? W1[(size_t)k * H + n0 + nl] : 0.f;
            T[kl0 + j * 4][nl] = f2bf(v);
        }
        __syncthreads();
        int kl = tid & 63, nl0 = tid >> 6;
#pragma unroll
        for (int j = 0; j < 16; j++) {
            int k = k0 + kl;
            if (k < Kp1) W1hT[(size_t)(n0 + nl0 + j * 4) * Kp1 + k] = T[kl][nl0 + j * 4];
        }
    } else if (b < bX + bT1 + bT2) {
        // W2 [512,512] -> W2hT [512,512]
        int t = b - bX - bT1;
        int kt = t >> 3, nt = t & 7;
        int k0 = kt * 64, n0 = nt * 64;
        int nl = tid & 63, kl0 = tid >> 6;
#pragma unroll
        for (int j = 0; j < 16; j++) {
            int k = k0 + kl0 + j * 4;
            T[kl0 + j * 4][nl] = f2bf(W2[(size_t)k * H + n0 + nl]);
        }
        __syncthreads();
        int kl = tid & 63, nl0 = tid >> 6;
#pragma unroll
        for (int j = 0; j < 16; j++)
            W2hT[(size_t)(n0 + nl0 + j * 4) * H + k0 + kl] = T[kl][nl0 + j * 4];
    } else {
        int e = (b - bX - bT1 - bT2) * 256 + tid;
        if (e < E) {
            int d = dst[e];
            int pos = atomicAdd(&deg[d], 1) & 63;   // mask: memory-safety guard, P(overflow)~1e-14
            csr_pad[d * 64 + pos] = src[e];
        }
    }
}

// ---------------- MFMA GEMM 128x128 (+ dinv blocks riding the dispatch) ----------------

#define TBK 32

__global__ __launch_bounds__(256) void gemm_mfma_kernel(
    const unsigned short* __restrict__ AhG,
    const unsigned short* __restrict__ WhT,
    unsigned short* __restrict__ Hb, int M, int N, int Kp, int tiles_m,
    int gemmBlocks,
    const int* __restrict__ deg, float* __restrict__ dinv, int nNodes)
{
    const int blk = blockIdx.x;
    if (blk >= gemmBlocks) {
        int i = (blk - gemmBlocks) * 256 + threadIdx.x;
        if (i < nNodes) dinv[i] = rsqrtf((float)deg[i] + 1.0f);
        return;
    }

    const int tn = blk & 3;          // N = 512 -> 4 col tiles of 128
    const int tm = blk >> 2;

    __shared__ unsigned short Ah[128 * TBK];   // 8 KB
    __shared__ unsigned short Bh[128 * TBK];   // 8 KB

    const int tid  = threadIdx.x;
    const int wave = tid >> 6;
    const int lane = tid & 63;
    const int quad = lane >> 4;
    const int l16  = lane & 15;
    const int row0 = tm * 128;
    const int col0 = tn * 128;
    const int wr = (wave >> 1) * 64;   // wave quadrant rows
    const int wc = (wave & 1) * 64;    // wave quadrant cols

    // staging: each wave stages 32 rows of A and 32 rows of B^T (2x gld16 each)
    const int srow = lane >> 2;
    const int skc  = (lane & 3) * 8;
    int ga0 = row0 + wave * 32 + srow;        if (ga0 >= M) ga0 = M - 1;
    int ga1 = row0 + wave * 32 + 16 + srow;   if (ga1 >= M) ga1 = M - 1;
    const unsigned short* gA0 = AhG + (size_t)ga0 * Kp + skc;
    const unsigned short* gA1 = AhG + (size_t)ga1 * Kp + skc;
    const unsigned short* gB0 = WhT + (size_t)(col0 + wave * 32 + srow) * Kp + skc;
    const unsigned short* gB1 = WhT + (size_t)(col0 + wave * 32 + 16 + srow) * Kp + skc;
    unsigned short* lA0 = &Ah[(wave * 32) * TBK];
    unsigned short* lA1 = &Ah[(wave * 32 + 16) * TBK];
    unsigned short* lB0 = &Bh[(wave * 32) * TBK];
    unsigned short* lB1 = &Bh[(wave * 32 + 16) * TBK];

    f32x4 acc[4][4];
#pragma unroll
    for (int b = 0; b < 4; b++)
#pragma unroll
        for (int c = 0; c < 4; c++) acc[b][c] = (f32x4){0.f, 0.f, 0.f, 0.f};

    for (int k0 = 0; k0 < Kp; k0 += TBK) {
        gld16(gA0 + k0, lA0);
        gld16(gA1 + k0, lA1);
        gld16(gB0 + k0, lB0);
        gld16(gB1 + k0, lB1);
        __syncthreads();

        short8 ah[4], bh[4];
#pragma unroll
        for (int b = 0; b < 4; b++)
            ah[b] = *(const short8*)&Ah[(wr + b * 16 + l16) * TBK + quad * 8];
#pragma unroll
        for (int c = 0; c < 4; c++)
            bh[c] = *(const short8*)&Bh[(wc + c * 16 + l16) * TBK + quad * 8];
#pragma unroll
        for (int c = 0; c < 4; c++)
#pragma unroll
            for (int b = 0; b < 4; b++)
                acc[b][c] = __builtin_amdgcn_mfma_f32_16x16x32_bf16(ah[b], bh[c], acc[b][c], 0, 0, 0);
        __syncthreads();
    }

#pragma unroll
    for (int b = 0; b < 4; b++) {
#pragma unroll
        for (int c = 0; c < 4; c++) {
            int gc = col0 + wc + c * 16 + l16;
#pragma unroll
            for (int r = 0; r < 4; r++) {
                int gr = row0 + wr + b * 16 + quad * 4 + r;
                if (gr < M) Hb[(size_t)gr * N + gc] = f2bf(acc[b][c][r]);
            }
        }
    }
}

// ---------------- gather aggregation, F=512 (layer 1): wave per node, bucket CSR ----------------

__global__ __launch_bounds__(256) void gather512_kernel(
    const unsigned short* __restrict__ hb,
    unsigned short* __restrict__ out_h,
    const int* __restrict__ csr_pad, const int* __restrict__ deg,
    const float* __restrict__ dinv, const float* __restrict__ bias, int n)
{
    const int wv = threadIdx.x >> 6;
    const int lane = threadIdx.x & 63;
    const int node = blockIdx.x * 4 + wv;
    if (node >= n) return;
    const float di = dinv[node];
    const int fo = lane * 8;
    const int base = node * 64;
    const int cnt = min(deg[node], 64);

    us8 self = *(const us8*)&hb[(size_t)node * 512 + fo];
    float4 b0 = *(const float4*)&bias[fo];
    float4 b1 = *(const float4*)&bias[fo + 4];
    const float dd = di * di;
    float acc[8];
    acc[0] = dd * bf2f(self[0]) + b0.x;
    acc[1] = dd * bf2f(self[1]) + b0.y;
    acc[2] = dd * bf2f(self[2]) + b0.z;
    acc[3] = dd * bf2f(self[3]) + b0.w;
    acc[4] = dd * bf2f(self[4]) + b1.x;
    acc[5] = dd * bf2f(self[5]) + b1.y;
    acc[6] = dd * bf2f(self[6]) + b1.z;
    acc[7] = dd * bf2f(self[7]) + b1.w;

    int p = 0;
    for (; p + 7 < cnt; p += 8) {
        int s[8];
#pragma unroll
        for (int u = 0; u < 8; u++) s[u] = csr_pad[base + p + u];
        us8 r[8];
#pragma unroll
        for (int u = 0; u < 8; u++) r[u] = *(const us8*)&hb[(size_t)s[u] * 512 + fo];
        float w[8];
#pragma unroll
        for (int u = 0; u < 8; u++) w[u] = dinv[s[u]] * di;
#pragma unroll
        for (int i = 0; i < 8; i++) {
            float t = acc[i];
#pragma unroll
            for (int u = 0; u < 8; u++) t += w[u] * bf2f(r[u][i]);
            acc[i] = t;
        }
    }
    for (; p + 3 < cnt; p += 4) {
        int s0 = csr_pad[base + p], s1 = csr_pad[base + p + 1];
        int s2 = csr_pad[base + p + 2], s3 = csr_pad[base + p + 3];
        float w0 = dinv[s0] * di, w1 = dinv[s1] * di, w2 = dinv[s2] * di, w3 = dinv[s3] * di;
        us8 r0 = *(const us8*)&hb[(size_t)s0 * 512 + fo];
        us8 r1 = *(const us8*)&hb[(size_t)s1 * 512 + fo];
        us8 r2 = *(const us8*)&hb[(size_t)s2 * 512 + fo];
        us8 r3 = *(const us8*)&hb[(size_t)s3 * 512 + fo];
#pragma unroll
        for (int i = 0; i < 8; i++)
            acc[i] += w0 * bf2f(r0[i]) + w1 * bf2f(r1[i]) + w2 * bf2f(r2[i]) + w3 * bf2f(r3[i]);
    }
    for (; p < cnt; ++p) {
        int s = csr_pad[base + p];
        float w = dinv[s] * di;
        us8 r = *(const us8*)&hb[(size_t)s * 512 + fo];
#pragma unroll
        for (int i = 0; i < 8; i++) acc[i] += w * bf2f(r[i]);
    }

    us8 o;
#pragma unroll
    for (int i = 0; i < 8; i++) o[i] = f2bf(fmaxf(acc[i], 0.f));
    *(us8*)&out_h[(size_t)node * 512 + fo] = o;
}

// ---------------- gather F=512 (layer 2) + fused classifier: h3[node][0..10] = relu(agg) @ Wc ----------------
// No AhB write; classifier uses pre-rounding f32 features (more accurate than bf16 path).

__global__ __launch_bounds__(256) void gather512c_kernel(
    const unsigned short* __restrict__ hb,
    const int* __restrict__ csr_pad, const int* __restrict__ deg,
    const float* __restrict__ dinv, const float* __restrict__ bias,
    const float* __restrict__ Wc, float* __restrict__ h3, int n)
{
    const int wv = threadIdx.x >> 6;
    const int lane = threadIdx.x & 63;
    const int node = blockIdx.x * 4 + wv;
    if (node >= n) return;
    const float di = dinv[node];
    const int fo = lane * 8;
    const int base = node * 64;
    const int cnt = min(deg[node], 64);

    us8 self = *(const us8*)&hb[(size_t)node * 512 + fo];
    float4 b0 = *(const float4*)&bias[fo];
    float4 b1 = *(const float4*)&bias[fo + 4];
    const float dd = di * di;
    float acc[8];
    acc[0] = dd * bf2f(self[0]) + b0.x;
    acc[1] = dd * bf2f(self[1]) + b0.y;
    acc[2] = dd * bf2f(self[2]) + b0.z;
    acc[3] = dd * bf2f(self[3]) + b0.w;
    acc[4] = dd * bf2f(self[4]) + b1.x;
    acc[5] = dd * bf2f(self[5]) + b1.y;
    acc[6] = dd * bf2f(self[6]) + b1.z;
    acc[7] = dd * bf2f(self[7]) + b1.w;

    int p = 0;
    for (; p + 7 < cnt; p += 8) {
        int s[8];
#pragma unroll
        for (int u = 0; u < 8; u++) s[u] = csr_pad[base + p + u];
        us8 r[8];
#pragma unroll
        for (int u = 0; u < 8; u++) r[u] = *(const us8*)&hb[(size_t)s[u] * 512 + fo];
        float w[8];
#pragma unroll
        for (int u = 0; u < 8; u++) w[u] = dinv[s[u]] * di;
#pragma unroll
        for (int i = 0; i < 8; i++) {
            float t = acc[i];
#pragma unroll
            for (int u = 0; u < 8; u++) t += w[u] * bf2f(r[u][i]);
            acc[i] = t;
        }
    }
    for (; p + 3 < cnt; p += 4) {
        int s0 = csr_pad[base + p], s1 = csr_pad[base + p + 1];
        int s2 = csr_pad[base + p + 2], s3 = csr_pad[base + p + 3];
        float w0 = dinv[s0] * di, w1 = dinv[s1] * di, w2 = dinv[s2] * di, w3 = dinv[s3] * di;
        us8 r0 = *(const us8*)&hb[(size_t)s0 * 512 + fo];
        us8 r1 = *(const us8*)&hb[(size_t)s1 * 512 + fo];
        us8 r2 = *(const us8*)&hb[(size_t)s2 * 512 + fo];
        us8 r3 = *(const us8*)&hb[(size_t)s3 * 512 + fo];
#pragma unroll
        for (int i = 0; i < 8; i++)
            acc[i] += w0 * bf2f(r0[i]) + w1 * bf2f(r1[i]) + w2 * bf2f(r2[i]) + w3 * bf2f(r3[i]);
    }
    for (; p < cnt; ++p) {
        int s = csr_pad[base + p];
        float w = dinv[s] * di;
        us8 r = *(const us8*)&hb[(size_t)s * 512 + fo];
#pragma unroll
        for (int i = 0; i < 8; i++) acc[i] += w * bf2f(r[i]);
    }

    // classifier: per-lane 8-feature slice x Wc rows fo..fo+7 (L1-resident, 8 B loads)
    float wcr[8][10];
#pragma unroll
    for (int i = 0; i < 8; i++) {
        const float2* wp = (const float2*)&Wc[(size_t)(fo + i) * 10];
#pragma unroll
        for (int j = 0; j < 5; j++) {
            float2 v = wp[j];
            wcr[i][2 * j] = v.x; wcr[i][2 * j + 1] = v.y;
        }
    }
    float pc[10];
#pragma unroll
    for (int c = 0; c < 10; c++) pc[c] = 0.f;
#pragma unroll
    for (int i = 0; i < 8; i++) {
        float r = fmaxf(acc[i], 0.f);
#pragma unroll
        for (int c = 0; c < 10; c++) pc[c] += r * wcr[i][c];
    }
#pragma unroll
    for (int c = 0; c < 10; c++) {
#pragma unroll
        for (int off = 1; off < 64; off <<= 1)
            pc[c] += __shfl_xor(pc[c], off);
    }
    if (lane == 0) {
#pragma unroll
        for (int c = 0; c < 10; c++) h3[(size_t)node * 10 + c] = pc[c];
    }
}

// ---------------- fused gather(F=10) + log_softmax: WAVE per node ----------------

__global__ __launch_bounds__(256) void gather10_softmax_kernel(
    const float* __restrict__ h3, float* __restrict__ out,
    const int* __restrict__ csr_pad, const int* __restrict__ deg,
    const float* __restrict__ dinv, const float* __restrict__ bc, int n)
{
    const int wv = threadIdx.x >> 6;
    const int lane = threadIdx.x & 63;
    const int node = blockIdx.x * 4 + wv;
    if (node >= n) return;

    const int eg = lane / 10;          // 0..5 (lane<60), 6 for lanes 60..63
    const int c  = lane - eg * 10;
    const bool active = lane < 60;
    const float di = dinv[node];
    const int base = node * 64;
    const int cnt = min(deg[node], 64);

    float acc = 0.f;
    if (active) {
        for (int p = eg; p < cnt; p += 6) {
            int s = csr_pad[base + p];
            acc += h3[(size_t)s * 10 + c] * dinv[s];
        }
        acc *= di;
    }
    // reduce eg-groups: lanes (c, c+10, ..., c+50) -> lane c
    acc += __shfl(acc, lane + 30);                         // lanes 0..29 pick up eg+3
    float t1 = __shfl(acc, lane + 10);
    float t2 = __shfl(acc, lane + 20);
    if (lane < 10) {
        acc = acc + t1 + t2 + h3[(size_t)node * 10 + c] * di * di + bc[c];
    }
    float vj[10];
#pragma unroll
    for (int j = 0; j < 10; j++) vj[j] = __shfl(acc, j);
    if (lane < 10) {
        float m = vj[0];
#pragma unroll
        for (int j = 1; j < 10; j++) m = fmaxf(m, vj[j]);
        float ssum = 0.f;
#pragma unroll
        for (int j = 0; j < 10; j++) ssum += __expf(vj[j] - m);
        out[(size_t)node * 10 + c] = acc - (m + __logf(ssum));
    }
}

// ---------------- launch ----------------

extern "C" void kernel_launch(void* const* d_in, const int* in_sizes, int n_in,
                              void* d_out, int out_size, void* d_ws, size_t ws_size,
                              hipStream_t stream)
{
    const float* x   = (const float*)d_in[0];
    const int*   ei  = (const int*)d_in[1];
    const float* W1  = (const float*)d_in[2];
    const float* b1  = (const float*)d_in[3];
    const float* W2  = (const float*)d_in[4];
    const float* b2  = (const float*)d_in[5];
    const float* Wc  = (const float*)d_in[6];
    const float* bc  = (const float*)d_in[7];
    float* out = (float*)d_out;

    const int IN_FEATS = 784;
    const int KP1 = 800;
    const int H = 512;
    const int NC = 10;
    const int n = in_sizes[0] / IN_FEATS;   // 10000
    const int E = in_sizes[1] / 2;          // 160000
    const int* src = ei;
    const int* dst = ei + E;

    // workspace layout (~41 MB)
    char* ws = (char*)d_ws;
    unsigned short* Hb   = (unsigned short*)ws; ws += (size_t)n * H * sizeof(unsigned short);
    unsigned short* Xh   = (unsigned short*)ws; ws += (size_t)n * KP1 * sizeof(unsigned short);
    unsigned short* AhB  = (unsigned short*)ws; ws += (size_t)n * H * sizeof(unsigned short);
    unsigned short* W1hT = (unsigned short*)ws; ws += (size_t)KP1 * H * sizeof(unsigned short);
    unsigned short* W2hT = (unsigned short*)ws; ws += (size_t)H * H * sizeof(unsigned short);
    float* dinv      = (float*)ws;             ws += (size_t)n * sizeof(float);
    int*   deg       = (int*)ws;               ws += (size_t)n * sizeof(int);
    int*   csr_pad   = (int*)ws;               ws += (size_t)n * 64 * sizeof(int);
    float* h3        = (float*)ws;             ws += (size_t)n * NC * sizeof(float);

    hipMemsetAsync(deg, 0, (size_t)n * sizeof(int), stream);

    // ---- fused prep (X conv + W transposes + deg count + bucket-CSR fill) ----
    const int bX  = ((size_t)n * (KP1 / 4) + 255) / 256;   // 7813
    const int bT1 = ((KP1 + 63) / 64) * (H / 64);          // 104
    const int bT2 = (H / 64) * (H / 64);                   // 64
    const int bE  = (E + 255) / 256;                       // 625
    prep_kernel<<<bX + bT1 + bT2 + bE, 256, 0, stream>>>(
        x, Xh, W1, W1hT, W2, W2hT, src, dst, deg, csr_pad,
        n, IN_FEATS, KP1, H, E, bX, bT1, bT2);

    const int tiles_m = (n + 127) / 128;                    // 79
    const int gemmBlocks = tiles_m * 4;                     // 316 (128x128 tiles, N=512)
    const int bN = (n + 255) / 256;                         // 40 dinv blocks

    // ---- layer 1 (+ dinv riding the dispatch) ----
    gemm_mfma_kernel<<<gemmBlocks + bN, 256, 0, stream>>>(
        Xh, W1hT, Hb, n, H, KP1, tiles_m, gemmBlocks, deg, dinv, n);
    gather512_kernel<<<(n + 3) / 4, 256, 0, stream>>>(Hb, AhB, csr_pad, deg, dinv, b1, n);

    // ---- layer 2 (+ fused classifier epilogue) ----
    gemm_mfma_kernel<<<gemmBlocks, 256, 0, stream>>>(
        AhB, W2hT, Hb, n, H, H, tiles_m, gemmBlocks, deg, dinv, 0);
    gather512c_kernel<<<(n + 3) / 4, 256, 0, stream>>>(Hb, csr_pad, deg, dinv, b2, Wc, h3, n);

    // ---- softmax layer ----
    gather10_softmax_kernel<<<(n + 3) / 4, 256, 0, stream>>>(h3, out, csr_pad, deg, dinv, bc, n);
}